// Round 7
// baseline (221.702 us; speedup 1.0000x reference)
//
#include <hip/hip_runtime.h>

#define NN 100000
#define NE 1200000
#define DD 64
#define NTILES 3125        // NN/32 exact
#define NBK 391            // buckets, 256 rows each (row>>8); NBK*256 = 100096
#define MLEN (NBK * 256)   // count-matrix length
#define EPB 4688           // ceil(NE/256) edges per bucket-pass block
#define ECAP 768           // LDS edge-stage capacity per 32-node block (mean 384)
#define NFB 16             // agg_final nodes per block (128 threads, 2 waves)
#define ECAPF 512          // agg_final edge-stage capacity (mean 192, +23 sigma)

typedef unsigned int uint32;
typedef unsigned char uint8;
typedef unsigned short ushort16;
typedef __attribute__((ext_vector_type(8))) short short8;    // 8 bf16 (4 VGPR)
typedef __attribute__((ext_vector_type(16))) float f32x16;   // MFMA 32x32 acc

__device__ __forceinline__ ushort16 f2bf(float x) {
    uint32 u = __float_as_uint(x);
    u += 0x7FFFu + ((u >> 16) & 1u);   // round-to-nearest-even
    return (ushort16)(u >> 16);
}
__device__ __forceinline__ float bflo(uint32 u) { return __uint_as_float(u << 16); }
__device__ __forceinline__ float bfhi(uint32 u) { return __uint_as_float(u & 0xFFFF0000u); }
__device__ __forceinline__ uint32 pack2(float a, float b) {
    return (uint32)f2bf(a) | ((uint32)f2bf(b) << 16);
}

// ---- gather loop (R2-proven: plain unroll-4, VGPR~40) -------------------
__device__ __forceinline__ void agg_lds(float* a, int ls, int le, uint32 flB,
                                        const uint2* __restrict__ esh,
                                        const char* __restrict__ ybase) {
    #pragma unroll 4
    for (int j = ls; j < le; j++) {
        uint2 ei = esh[j];                       // (col*128, w bits)
        float w = __uint_as_float(ei.y);
        uint4 yv = *(const uint4*)(ybase + (ei.x + flB));
        a[0] = fmaf(bflo(yv.x), w, a[0]);
        a[1] = fmaf(bfhi(yv.x), w, a[1]);
        a[2] = fmaf(bflo(yv.y), w, a[2]);
        a[3] = fmaf(bfhi(yv.y), w, a[3]);
        a[4] = fmaf(bflo(yv.z), w, a[4]);
        a[5] = fmaf(bfhi(yv.z), w, a[5]);
        a[6] = fmaf(bflo(yv.w), w, a[6]);
        a[7] = fmaf(bfhi(yv.w), w, a[7]);
    }
}

// Cold fallback if a block exceeds its LDS edge-stage capacity.
__device__ __forceinline__ void agg_glob(float* a, int s, int e, uint32 flB,
                                         const uint32* __restrict__ edges,
                                         const char* __restrict__ ybase) {
    for (int j = s; j < e; j++) {
        uint32 ed = edges[j];
        float w = (float)(ed & 32767u) * (1.0f / 32767.0f);
        uint4 yv = *(const uint4*)(ybase + (((ed >> 15) << 7) + flB));
        a[0] = fmaf(bflo(yv.x), w, a[0]);
        a[1] = fmaf(bfhi(yv.x), w, a[1]);
        a[2] = fmaf(bflo(yv.y), w, a[2]);
        a[3] = fmaf(bfhi(yv.y), w, a[3]);
        a[4] = fmaf(bflo(yv.z), w, a[4]);
        a[5] = fmaf(bfhi(yv.z), w, a[5]);
        a[6] = fmaf(bflo(yv.w), w, a[6]);
        a[7] = fmaf(bfhi(yv.w), w, a[7]);
    }
}

// ---- Merged launch 1: bucket count (blocks 0..255) + W pre-pack (256..261)
//      + layer-1 GEMM (262..652, self-packs its W -> no intra-launch dep) --

__global__ __launch_bounds__(512)
void k_init(const int* __restrict__ row, int* __restrict__ M,
            const float* __restrict__ selfk, const float* __restrict__ neighk,
            short8* __restrict__ wpack, const float* __restrict__ x,
            ushort16* __restrict__ hs, ushort16* __restrict__ y,
            const float* __restrict__ biases) {
    if (blockIdx.x >= 262) {
        // ---- layer-1 GEMM: hs = x@Ws + b (bf16), y = x@Wn (bf16) ----
        int lane  = threadIdx.x & 63;
        int wave  = threadIdx.x >> 6;                  // 0..7
        int wid   = (blockIdx.x - 262) * 8 + wave;     // 0..3127
        int mrow  = lane & 31;
        int khalf = lane >> 5;
        int t     = wid & 1;

        short8 Wf[2][4];
        #pragma unroll
        for (int g = 0; g < 2; g++) {
            const float* W = g ? neighk : selfk;       // layer 0
            #pragma unroll
            for (int s = 0; s < 4; s++) {
                int k0 = s * 16 + khalf * 8;
                short8 v;
                #pragma unroll
                for (int j = 0; j < 8; j++)
                    v[j] = (short)f2bf(W[(k0 + j) * 64 + t * 32 + mrow]);
                Wf[g][s] = v;
            }
        }
        float bval = biases[t * 32 + mrow];

        for (int tile = wid >> 1; tile < NTILES; tile += 1564) {
            int n0 = tile * 32;
            const float4* hf4 = (const float4*)(x + (size_t)(n0 + mrow) * 64)
                                + khalf * 2;
            short8 A[4];
            #pragma unroll
            for (int s = 0; s < 4; s++) {
                float4 q0 = hf4[s * 4];
                float4 q1 = hf4[s * 4 + 1];
                short8 a;
                a[0] = (short)f2bf(q0.x); a[1] = (short)f2bf(q0.y);
                a[2] = (short)f2bf(q0.z); a[3] = (short)f2bf(q0.w);
                a[4] = (short)f2bf(q1.x); a[5] = (short)f2bf(q1.y);
                a[6] = (short)f2bf(q1.z); a[7] = (short)f2bf(q1.w);
                A[s] = a;
            }

            f32x16 acc0, acc1;
            #pragma unroll
            for (int r = 0; r < 16; r++) { acc0[r] = 0.f; acc1[r] = 0.f; }

            #pragma unroll
            for (int s = 0; s < 4; s++) {
                acc0 = __builtin_amdgcn_mfma_f32_32x32x16_bf16(A[s], Wf[0][s], acc0, 0, 0, 0);
                acc1 = __builtin_amdgcn_mfma_f32_32x32x16_bf16(A[s], Wf[1][s], acc1, 0, 0, 0);
            }

            int colbase = t * 32 + mrow;
            #pragma unroll
            for (int r = 0; r < 16; r++) {
                int rw = (r & 3) + 8 * (r >> 2) + 4 * khalf;
                int nn = n0 + rw;
                hs[nn * DD + colbase] = f2bf(acc0[r] + bval);
                y [nn * DD + colbase] = f2bf(acc1[r]);
            }
        }
        return;
    }
    if (blockIdx.x >= 256) {
        int tid = (blockIdx.x - 256) * 512 + threadIdx.x;   // 0..3071
        if (tid < 3 * 16 * 64) {
            int lane  = tid & 63;
            int frag  = (tid >> 6) & 15;
            int layer = tid >> 10;
            int g = frag >> 3;
            int t = (frag >> 2) & 1;
            int s = frag & 3;
            const float* W = (g ? neighk : selfk) + layer * 4096;
            int n = t * 32 + (lane & 31);
            int k0 = s * 16 + (lane >> 5) * 8;
            short8 v;
            #pragma unroll
            for (int j = 0; j < 8; j++) v[j] = (short)f2bf(W[(k0 + j) * 64 + n]);
            wpack[tid] = v;
        }
        return;
    }
    __shared__ int bins[NBK];
    for (int i = threadIdx.x; i < NBK; i += 512) bins[i] = 0;
    __syncthreads();
    int start = blockIdx.x * EPB;
    int end = min(start + EPB, NE);
    for (int e = start + (int)threadIdx.x; e < end; e += 512)
        atomicAdd(&bins[row[e] >> 8], 1);
    __syncthreads();
    for (int i = threadIdx.x; i < NBK; i += 512)
        M[i * 256 + blockIdx.x] = bins[i];
}

// ---- CSR build ----------------------------------------------------------

__global__ void k_scan1(const int* __restrict__ in, int* __restrict__ outx,
                        int* __restrict__ partials) {
    __shared__ int tmp[256];
    int t = threadIdx.x;
    int i = blockIdx.x * 256 + t;
    int v = (i < MLEN) ? in[i] : 0;
    tmp[t] = v;
    __syncthreads();
    #pragma unroll
    for (int off = 1; off < 256; off <<= 1) {
        int add = (t >= off) ? tmp[t - off] : 0;
        __syncthreads();
        tmp[t] += add;
        __syncthreads();
    }
    if (i < MLEN) outx[i] = tmp[t] - v;            // exclusive (within block)
    if (t == 255) partials[blockIdx.x] = tmp[255]; // block total (raw)
}

// Every bscatter block inline-scans the 391 raw bucket totals (9 LDS
// rounds); block 0 publishes the scan for k_build.
__global__ __launch_bounds__(512)
void k_bscatter(const int* __restrict__ row, const int* __restrict__ col,
                const float* __restrict__ ew, const int* __restrict__ Mscan,
                const int* __restrict__ partials, int* __restrict__ partials2,
                uint32* __restrict__ colw, uint8* __restrict__ rowlo) {
    __shared__ int tmp[512];
    __shared__ int cur[NBK];
    int t = threadIdx.x;
    int v = (t < NBK) ? partials[t] : 0;
    tmp[t] = v;
    __syncthreads();
    #pragma unroll
    for (int off = 1; off < 512; off <<= 1) {
        int add = (t >= off) ? tmp[t - off] : 0;
        __syncthreads();
        tmp[t] += add;
        __syncthreads();
    }
    if (t < NBK) {
        int excl = tmp[t] - v;
        cur[t] = Mscan[t * 256 + blockIdx.x] + excl;
        if (blockIdx.x == 0) partials2[t] = excl;
    }
    __syncthreads();
    int start = blockIdx.x * EPB;
    int end = min(start + EPB, NE);
    for (int e = start + (int)threadIdx.x; e < end; e += 512) {
        int r = row[e];
        int wq = (int)(ew[e] * 32767.0f + 0.5f);
        wq = (wq > 32767) ? 32767 : wq;
        int p = atomicAdd(&cur[r >> 8], 1);
        colw[p]  = ((uint32)col[e] << 15) | (uint32)wq;
        rowlo[p] = (uint8)(r & 255);
    }
}

// k_build: (row x 16 col-range) counting sort. Edges within each row come
// out sorted by col>>13 -> during agg all groups sweep col-space together;
// the concurrent frontier fits per-XCD L2. (R6: -12us, verified.)
__global__ __launch_bounds__(256)
void k_build(const int* __restrict__ Mscan, const int* __restrict__ partials2,
             const uint32* __restrict__ colw, const uint8* __restrict__ rowlo,
             uint32* __restrict__ edges, int* __restrict__ offsets) {
    __shared__ int bins[256 * 16];   // (rowlo, colrange) counters -> cursors
    __shared__ int tmp[256];
    int b = blockIdx.x;
    int t = threadIdx.x;
    int bstart = Mscan[b * 256] + partials2[b];
    int bend   = (b == NBK - 1) ? NE : Mscan[(b + 1) * 256] + partials2[b + 1];
    for (int k = t; k < 4096; k += 256) bins[k] = 0;
    __syncthreads();
    for (int p = bstart + t; p < bend; p += 256) {
        uint32 cw = colw[p];
        int cr = (int)(cw >> 28);          // col>>13, col<2^17 -> 0..12
        atomicAdd(&bins[rowlo[p] * 16 + cr], 1);
    }
    __syncthreads();
    int base16 = t * 16;
    int own = 0;
    #pragma unroll
    for (int k = 0; k < 16; k++) {
        int v = bins[base16 + k];
        bins[base16 + k] = own;
        own += v;
    }
    tmp[t] = own;
    __syncthreads();
    #pragma unroll
    for (int off = 1; off < 256; off <<= 1) {
        int add = (t >= off) ? tmp[t - off] : 0;
        __syncthreads();
        tmp[t] += add;
        __syncthreads();
    }
    int rowbase = bstart + (tmp[t] - own);   // exclusive prefix for this row
    #pragma unroll
    for (int k = 0; k < 16; k++) bins[base16 + k] += rowbase;
    int rowid = b * 256 + t;
    if (rowid < NN) offsets[rowid] = rowbase;
    if (b == 0 && t == 0) offsets[NN] = NE;
    __syncthreads();
    for (int p = bstart + t; p < bend; p += 256) {
        uint32 cw = colw[p];
        int cr = (int)(cw >> 28);
        int dst = atomicAdd(&bins[rowlo[p] * 16 + cr], 1);
        edges[dst] = cw;                 // block-private range: full lines
    }
}

// ---- Fused agg + next-layer GEMM (unchanged from R6) --------------------

__global__ __launch_bounds__(256)
void agg_gemm(const uint4* __restrict__ hs4, const uint4* __restrict__ y4,
              ushort16* __restrict__ hs_out, ushort16* __restrict__ y_out,
              const int* __restrict__ offsets, const uint32* __restrict__ edges,
              const short8* __restrict__ wpack, const float* __restrict__ bias) {
    __shared__ uint32 sh[32 * 36];
    __shared__ uint2 esh[ECAP];
    int lane = threadIdx.x & 63;
    int wave = threadIdx.x >> 6;
    int g  = lane >> 3;          // group 0..7 -> node
    int fl = lane & 7;           // feature octet
    int n0 = blockIdx.x * 32;
    int lrow = wave * 8 + g;     // 0..31
    int n = n0 + lrow;

    int ebase = offsets[n0];
    int m = min(offsets[n0 + 32] - ebase, ECAP);
    for (int i = threadIdx.x; i < m; i += 256) {
        uint32 ed = edges[ebase + i];
        esh[i] = make_uint2((ed >> 15) << 7,
                            __float_as_uint((float)(ed & 32767u) * (1.0f / 32767.0f)));
    }
    int s = offsets[n];
    int e = offsets[n + 1];
    uint4 hv = hs4[n * 8 + fl];
    __syncthreads();

    float a[8] = {bflo(hv.x), bfhi(hv.x), bflo(hv.y), bfhi(hv.y),
                  bflo(hv.z), bfhi(hv.z), bflo(hv.w), bfhi(hv.w)};
    uint32 flB = (uint32)fl * 16u;
    const char* ybase = (const char*)y4;
    int ls = s - ebase, le = e - ebase;
    agg_lds(a, min(ls, ECAP), min(le, ECAP), flB, esh, ybase);
    if (le > ECAP)
        agg_glob(a, ebase + max(ls, ECAP), ebase + le, flB, edges, ybase);

    uint32* dstp = &sh[lrow * 36 + fl * 4];
    dstp[0] = pack2(fmaxf(a[0], 0.f), fmaxf(a[1], 0.f));
    dstp[1] = pack2(fmaxf(a[2], 0.f), fmaxf(a[3], 0.f));
    dstp[2] = pack2(fmaxf(a[4], 0.f), fmaxf(a[5], 0.f));
    dstp[3] = pack2(fmaxf(a[6], 0.f), fmaxf(a[7], 0.f));
    __syncthreads();

    // gemm phase
    int mrow  = lane & 31;
    int khalf = lane >> 5;
    int gsel  = wave >> 1;       // 0=self(hs) 1=neigh(y)
    int t     = wave & 1;        // col half

    short8 Wf[4];
    #pragma unroll
    for (int ss = 0; ss < 4; ss++)
        Wf[ss] = wpack[(((gsel * 2 + t) * 4) + ss) * 64 + lane];

    short8 A[4];
    #pragma unroll
    for (int ss = 0; ss < 4; ss++)
        A[ss] = *(const short8*)&sh[mrow * 36 + ss * 8 + khalf * 4];   // 16B, aligned

    f32x16 acc;
    #pragma unroll
    for (int r = 0; r < 16; r++) acc[r] = 0.f;
    #pragma unroll
    for (int ss = 0; ss < 4; ss++)
        acc = __builtin_amdgcn_mfma_f32_32x32x16_bf16(A[ss], Wf[ss], acc, 0, 0, 0);

    float bval = gsel ? 0.f : bias[t * 32 + mrow];
    ushort16* dst = gsel ? y_out : hs_out;
    int colbase = t * 32 + mrow;
    #pragma unroll
    for (int r = 0; r < 16; r++) {
        int rw = (r & 3) + 8 * (r >> 2) + 4 * khalf;
        dst[(n0 + rw) * DD + colbase] = f2bf(acc[r] + bval);
    }
}

// ---- Final aggregate: out = relu(hs[n] + sum_j w_j * y[col_j]), f32 ----
// OCCUPANCY EXPERIMENT: 128-thread blocks (2 waves, 16 nodes). agg_* shows
// only ~47% occupancy (~3.75 blocks/CU) despite VGPR 40 / LDS 10.75KB; if
// the limiter is blocks-per-CU, 2-wave blocks can reach 32 waves/CU under
// a ~16-workgroup/CU cap -> 2x in-flight gather requests. Discriminates
// "request-queue cap" (null result) vs "wave-occupancy cap" (win).

__global__ __launch_bounds__(128)
void agg_final(const uint4* __restrict__ hs4, const uint4* __restrict__ y4,
               float4* __restrict__ out, const int* __restrict__ offsets,
               const uint32* __restrict__ edges) {
    __shared__ uint2 esh[ECAPF];
    int tid  = threadIdx.x;
    int lane = tid & 63;
    int wave = tid >> 6;         // 0..1
    int g  = lane >> 3;
    int fl = lane & 7;
    int n0 = blockIdx.x * NFB;
    int n = n0 + wave * 8 + g;   // 6250*16 == NN exact

    int ebase = offsets[n0];
    int m = min(offsets[n0 + NFB] - ebase, ECAPF);
    for (int i = tid; i < m; i += 128) {
        uint32 ed = edges[ebase + i];
        esh[i] = make_uint2((ed >> 15) << 7,
                            __float_as_uint((float)(ed & 32767u) * (1.0f / 32767.0f)));
    }
    int s = offsets[n];
    int e = offsets[n + 1];
    uint4 hv = hs4[n * 8 + fl];
    __syncthreads();

    float a[8] = {bflo(hv.x), bfhi(hv.x), bflo(hv.y), bfhi(hv.y),
                  bflo(hv.z), bfhi(hv.z), bflo(hv.w), bfhi(hv.w)};
    uint32 flB = (uint32)fl * 16u;
    const char* ybase = (const char*)y4;
    int ls = s - ebase, le = e - ebase;
    agg_lds(a, min(ls, ECAPF), min(le, ECAPF), flB, esh, ybase);
    if (le > ECAPF)
        agg_glob(a, ebase + max(ls, ECAPF), ebase + le, flB, edges, ybase);

    out[n * 16 + fl * 2]     = make_float4(fmaxf(a[0], 0.f), fmaxf(a[1], 0.f),
                                           fmaxf(a[2], 0.f), fmaxf(a[3], 0.f));
    out[n * 16 + fl * 2 + 1] = make_float4(fmaxf(a[4], 0.f), fmaxf(a[5], 0.f),
                                           fmaxf(a[6], 0.f), fmaxf(a[7], 0.f));
}

// ---- launch -------------------------------------------------------------

extern "C" void kernel_launch(void* const* d_in, const int* in_sizes, int n_in,
                              void* d_out, int out_size, void* d_ws, size_t ws_size,
                              hipStream_t stream) {
    const float* x      = (const float*)d_in[0];
    const int*   ei     = (const int*)d_in[1];
    const float* ew     = (const float*)d_in[2];
    const float* selfk  = (const float*)d_in[3];
    const float* neighk = (const float*)d_in[4];
    const float* biases = (const float*)d_in[5];
    float* out = (float*)d_out;

    char* w = (char*)d_ws;
    ushort16* hsA   = (ushort16*)w; w += (size_t)NN * DD * sizeof(ushort16);
    ushort16* yA    = (ushort16*)w; w += (size_t)NN * DD * sizeof(ushort16);
    ushort16* hsB   = (ushort16*)w; w += (size_t)NN * DD * sizeof(ushort16);
    ushort16* yB    = (ushort16*)w; w += (size_t)NN * DD * sizeof(ushort16);
    uint32* edges   = (uint32*)w;   w += (size_t)NE * sizeof(uint32);
    uint32* colwB   = (uint32*)w;   w += (size_t)NE * sizeof(uint32);
    uint8*  rowlo   = (uint8*)w;    w += (size_t)NE * sizeof(uint8);
    w = (char*)(((size_t)w + 255) & ~(size_t)255);
    int*    M       = (int*)w;      w += (size_t)MLEN * sizeof(int);
    int*    Mscan   = (int*)w;      w += (size_t)MLEN * sizeof(int);
    int*    offsets = (int*)w;      w += (size_t)(NN + 1) * sizeof(int);
    int*    partials= (int*)w;      w += 512 * sizeof(int);
    int*    partials2=(int*)w;      w += 512 * sizeof(int);
    short8* wpack   = (short8*)w;   w += (size_t)3 * 16 * 64 * sizeof(short8);

    const int* row = ei;
    const int* col = ei + NE;

    // 1: bucket count + wpack + layer-1 GEMM (independent work, one launch)
    k_init    <<<653, 512, 0, stream>>>(row, M, selfk, neighk, wpack,
                                        x, hsA, yA, biases);
    k_scan1   <<<NBK, 256, 0, stream>>>(M, Mscan, partials);
    k_bscatter<<<256, 512, 0, stream>>>(row, col, ew, Mscan, partials, partials2,
                                        colwB, rowlo);
    k_build   <<<NBK, 256, 0, stream>>>(Mscan, partials2, colwB, rowlo, edges, offsets);

    // agg(layer1) + GEMM(layer2): -> hsB, yB
    agg_gemm <<<NTILES, 256, 0, stream>>>((const uint4*)hsA, (const uint4*)yA,
                                          hsB, yB, offsets, edges,
                                          wpack + 1024, biases + 64);
    // agg(layer2) + GEMM(layer3): -> hsA, yA
    agg_gemm <<<NTILES, 256, 0, stream>>>((const uint4*)hsB, (const uint4*)yB,
                                          hsA, yA, offsets, edges,
                                          wpack + 2048, biases + 128);
    // final aggregate -> out (f32)
    agg_final<<<NN / NFB, 128, 0, stream>>>((const uint4*)hsA, (const uint4*)yA,
                                            (float4*)out, offsets, edges);
}